// Round 3
// baseline (1111.246 us; speedup 1.0000x reference)
//
#include <hip/hip_runtime.h>
#include <hip/hip_bf16.h>

typedef _Float16 h2_t  __attribute__((ext_vector_type(2)));
typedef _Float16 f16x8 __attribute__((ext_vector_type(8)));
typedef float    f32x4 __attribute__((ext_vector_type(4)));

#define NLG    196608
#define DIM    256
#define NRELS  237
#define BG     128
#define NN     256
#define MM     (BG*NN)      // 32768
#define G3     768          // 3*DIM
#define NSPLIT 128
#define GPB    16           // graphs per gru block

// ---------------- A0: needed-relation flags ----------------
__global__ void k_needed(const int* __restrict__ rel, int* __restrict__ needed){
  int t = threadIdx.x;
  needed[t] = 0;
  __syncthreads();
  if (t < BG) atomicOr(&needed[rel[t]], 1);
}

// ---------------- A1: skip-filtered partial segment sums ----------------
__global__ __launch_bounds__(256) void k_segsum(const float* __restrict__ lgf,
    const int* __restrict__ lgt, const int* __restrict__ needed,
    float* __restrict__ part, int* __restrict__ cntp){
  int split = blockIdx.x >> 2, chunk = blockIdx.x & 3;
  int c0 = chunk * 64;
  __shared__ float acc[NRELS*64];
  __shared__ int   cacc[NRELS];
  __shared__ int   sneed[NRELS];
  int t = threadIdx.x, lane = t & 63, wv = t >> 6;
  for (int i = t; i < NRELS*64; i += 256) acc[i] = 0.f;
  for (int i = t; i < NRELS; i += 256){ cacc[i] = 0; sneed[i] = needed[i]; }
  __syncthreads();
  const int RPS = NLG / NSPLIT;
  int rbase = split * RPS;
  for (int it = 0; it < RPS/8; ++it){
    int r0 = rbase + it*8 + wv*2;
    int ty0 = lgt[r0], ty1 = lgt[r0+1];
    int nd0 = sneed[ty0], nd1 = sneed[ty1];
    float v0 = 0.f, v1 = 0.f;
    if (nd0) v0 = lgf[(size_t)r0*DIM + c0 + lane];
    if (nd1) v1 = lgf[(size_t)(r0+1)*DIM + c0 + lane];
    if (nd0){ atomicAdd(&acc[ty0*64 + lane], v0);
              if (chunk==0 && lane==0) atomicAdd(&cacc[ty0], 1); }
    if (nd1){ atomicAdd(&acc[ty1*64 + lane], v1);
              if (chunk==0 && lane==0) atomicAdd(&cacc[ty1], 1); }
  }
  __syncthreads();
  for (int i = t; i < NRELS*64; i += 256){
    int r = i >> 6, d = i & 63;
    part[((size_t)split*NRELS + r)*DIM + c0 + d] = acc[i];
  }
  if (chunk==0) for (int i = t; i < NRELS; i += 256) cntp[split*NRELS + i] = cacc[i];
}

// ---------------- A2: reduce partials -> means ----------------
__global__ __launch_bounds__(256) void k_means(const float* __restrict__ part,
      const int* __restrict__ cntp, float* __restrict__ means){
  int r = blockIdx.x, d = threadIdx.x;
  float s = 0.f;
  for (int sp = 0; sp < NSPLIT; ++sp) s += part[((size_t)sp*NRELS + r)*DIM + d];
  int c = 0;
  for (int sp = 0; sp < NSPLIT; ++sp) c += cntp[sp*NRELS + r];
  means[r*DIM + d] = (c > 0) ? (s / (float)c) : 0.f;
}

// ---------------- B0: X16 = f16(relu(emds+bias)), h0 = max_n(node) ----------------
__global__ __launch_bounds__(256) void k_prep(const float* __restrict__ emds,
     const float* __restrict__ gbias, _Float16* __restrict__ X16, float* __restrict__ h0){
  int b = blockIdx.x, d = threadIdx.x;
  float bi = gbias[d];
  float mx = -3.4e38f;
  const float* src = emds + (size_t)b*NN*DIM + d;
  _Float16* dst = X16 + (size_t)b*NN*DIM + d;
  #pragma unroll 4
  for (int n = 0; n < NN; ++n){
    float v = src[(size_t)n*DIM];
    mx = fmaxf(mx, v);
    dst[(size_t)n*DIM] = (_Float16)fmaxf(v + bi, 0.f);
  }
  h0[b*DIM + d] = mx;
}

// ---------------- B2: w_ih_b -> f16 row-major [768][256] ----------------
__global__ __launch_bounds__(256) void k_wconv(const float* __restrict__ wih,
      f16x8* __restrict__ wih16){
  int tid = blockIdx.x*256 + threadIdx.x;   // 0..24575
  int c = tid / G3, j = tid - c*G3;
  const float* s2 = wih + (size_t)j*DIM + c*8;
  f16x8 v;
  #pragma unroll
  for (int e = 0; e < 8; ++e) v[e] = (_Float16)s2[e];
  wih16[(size_t)j*32 + c] = v;
}

// ---------------- C: gi16[t][g][768] = f16(X @ w_ih_b^T + b_ih_b + bhh_fold) ----
__global__ __launch_bounds__(256) void k_gemm_gi(const _Float16* __restrict__ X16,
        const _Float16* __restrict__ wih16, const float* __restrict__ bih,
        const float* __restrict__ bhh, _Float16* __restrict__ gi16){
  __shared__ __align__(16) _Float16 Xs[64*136];
  __shared__ __align__(16) _Float16 Ws[64*136];
  int m0 = (blockIdx.x / 12) * 64;
  int n0 = (blockIdx.x % 12) * 64;
  int tix = threadIdx.x;
  int w = tix >> 6, l = tix & 63;
  int wm = (w & 1) * 32, wn = (w >> 1) * 32;
  int fr = l & 15, kg = l >> 4;
  f32x4 acc[2][2] = {};
  for (int kh = 0; kh < 2; ++kh){
    if (kh) __syncthreads();
    for (int rnd = 0; rnd < 4; ++rnd){
      int chunk = rnd*256 + tix;
      int r = chunk >> 4, cc = chunk & 15;
      *(f16x8*)&Xs[r*136 + cc*8] = *(const f16x8*)&X16[(size_t)(m0+r)*DIM + kh*128 + cc*8];
      *(f16x8*)&Ws[r*136 + cc*8] = *(const f16x8*)&wih16[(size_t)(n0+r)*DIM + kh*128 + cc*8];
    }
    __syncthreads();
    #pragma unroll
    for (int kk = 0; kk < 4; ++kk){
      int kcol = kk*32 + kg*8;
      f16x8 a0 = *(const f16x8*)&Xs[(wm + fr)*136 + kcol];
      f16x8 a1 = *(const f16x8*)&Xs[(wm + 16 + fr)*136 + kcol];
      f16x8 b0 = *(const f16x8*)&Ws[(wn + fr)*136 + kcol];
      f16x8 b1 = *(const f16x8*)&Ws[(wn + 16 + fr)*136 + kcol];
      acc[0][0] = __builtin_amdgcn_mfma_f32_16x16x32_f16(a0,b0,acc[0][0],0,0,0);
      acc[0][1] = __builtin_amdgcn_mfma_f32_16x16x32_f16(a0,b1,acc[0][1],0,0,0);
      acc[1][0] = __builtin_amdgcn_mfma_f32_16x16x32_f16(a1,b0,acc[1][0],0,0,0);
      acc[1][1] = __builtin_amdgcn_mfma_f32_16x16x32_f16(a1,b1,acc[1][1],0,0,0);
    }
  }
  // bias (b_ih + b_hh fold for r,z gates i.e. col<512)
  int col0 = n0 + wn + fr;
  float bv0 = bih[col0] + (col0 < 512 ? bhh[col0] : 0.f);
  float bv1 = bih[col0+16] + (col0+16 < 512 ? bhh[col0+16] : 0.f);
  __syncthreads();
  _Float16* stage = (_Float16*)Xs;     // 64 x 72 (pad) staging
  #pragma unroll
  for (int i = 0; i < 2; ++i)
  #pragma unroll
  for (int j = 0; j < 2; ++j){
    float bv = j ? bv1 : bv0;
    #pragma unroll
    for (int v = 0; v < 4; ++v){
      int srow = wm + i*16 + kg*4 + v;
      int scol = wn + j*16 + fr;
      stage[srow*72 + scol] = (_Float16)(acc[i][j][v] + bv);
    }
  }
  __syncthreads();
  {
    int r = tix >> 2, ch = tix & 3;
    int t0 = m0 & 255, gg = m0 >> 8;
    const f16x8* src = (const f16x8*)(stage + r*72 + ch*16);
    _Float16* dst = gi16 + (size_t)(t0 + r)*(BG*G3) + (size_t)gg*G3 + n0 + ch*16;
    *(f16x8*)(dst)   = src[0];
    *(f16x8*)(dst+8) = src[1];
  }
}

// ---- helpers for k_gru_bwd ----
__device__ __forceinline__ uint2 pack4(float a, float b, float c, float d){
  h2_t p0; p0[0] = (_Float16)a; p0[1] = (_Float16)b;
  h2_t p1; p1[0] = (_Float16)c; p1[1] = (_Float16)d;
  uint2 r; r.x = __builtin_bit_cast(unsigned int, p0);
  r.y = __builtin_bit_cast(unsigned int, p1);
  return r;
}
__device__ __forceinline__ f32x4 cvt4(uint2 u){
  h2_t a = __builtin_bit_cast(h2_t, u.x), b = __builtin_bit_cast(h2_t, u.y);
  f32x4 r; r[0]=(float)a[0]; r[1]=(float)a[1]; r[2]=(float)b[0]; r[3]=(float)b[1];
  return r;
}
__device__ __forceinline__ float sigf(float x){
  return __builtin_amdgcn_rcpf(1.f + __expf(-x));
}
__device__ __forceinline__ float tanhff(float x){
  float e = __expf(2.f*x);
  return 1.f - 2.f*__builtin_amdgcn_rcpf(e + 1.f);
}

// ---------------- D: backward GRU, MFMA, weights in VGPRs ----------------
// 8 blocks x 512 threads. Block owns 16 graphs. Wave w owns dims w*32..w*32+31
// for all three gates (6 m-tiles). N dimension of MFMA = 16 graphs.
__global__ __launch_bounds__(512, 2) void k_gru_bwd(
    const float* __restrict__ whh, const _Float16* __restrict__ gi16,
    const float* __restrict__ h0, const float* __restrict__ bhh,
    float* __restrict__ bwd1, float* __restrict__ bwd0){
  __shared__ __align__(16) _Float16 h16[GPB*256];
  char* h16b = (char*)h16;
  const int tid = threadIdx.x;
  const int w = tid >> 6, l = tid & 63;
  const int lq = l >> 4, fr = l & 15;
  const int g0 = blockIdx.x * GPB;
  const int gg = g0 + fr;                  // this lane's graph
  const int dbase = w*32 + lq*4;           // + dt*16 + v

  // ---- W fragments resident in VGPRs: wf[gate*2+dt][kc] ----
  f16x8 wf[6][8];
  #pragma unroll
  for (int gate = 0; gate < 3; ++gate)
  #pragma unroll
  for (int dt = 0; dt < 2; ++dt){
    const float* wr = whh + (size_t)(gate*256 + w*32 + dt*16 + fr)*256 + lq*8;
    #pragma unroll
    for (int kc = 0; kc < 8; ++kc){
      float4 x = *(const float4*)(wr + kc*32);
      float4 y = *(const float4*)(wr + kc*32 + 4);
      f16x8 f;
      f[0]=(_Float16)x.x; f[1]=(_Float16)x.y; f[2]=(_Float16)x.z; f[3]=(_Float16)x.w;
      f[4]=(_Float16)y.x; f[5]=(_Float16)y.y; f[6]=(_Float16)y.z; f[7]=(_Float16)y.w;
      wf[gate*2+dt][kc] = f;
    }
  }
  // ---- h_old (f32 regs), h16 init, b_hh_n regs ----
  float ho[2][4];
  float bn[2][4];
  #pragma unroll
  for (int dt = 0; dt < 2; ++dt){
    float4 h4 = *(const float4*)(h0 + (size_t)gg*DIM + dbase + dt*16);
    ho[dt][0]=h4.x; ho[dt][1]=h4.y; ho[dt][2]=h4.z; ho[dt][3]=h4.w;
    *(uint2*)(h16b + ((fr*512 + w*64 + dt*32 + lq*8) ^ ((fr&7)<<4)))
        = pack4(h4.x, h4.y, h4.z, h4.w);
    float4 b4 = *(const float4*)(bhh + 512 + dbase + dt*16);
    bn[dt][0]=b4.x; bn[dt][1]=b4.y; bn[dt][2]=b4.z; bn[dt][3]=b4.w;
  }
  // ---- gi prefetch (t = 255) ----
  const char* gp = (const char*)gi16 + ((size_t)255*BG*G3 + (size_t)gg*G3 + dbase)*2;
  uint2 gc[6], gn[6];
  #pragma unroll
  for (int gate = 0; gate < 3; ++gate)
  #pragma unroll
  for (int dt = 0; dt < 2; ++dt)
    gc[gate*2+dt] = *(const uint2*)(gp + gate*512 + dt*32);
  __syncthreads();

  for (int s = 0; s < 256; ++s){
    // prefetch next timestep's gi
    if (s < 255){
      gp -= (size_t)BG*G3*2;
      #pragma unroll
      for (int gate = 0; gate < 3; ++gate)
      #pragma unroll
      for (int dt = 0; dt < 2; ++dt)
        gn[gate*2+dt] = *(const uint2*)(gp + gate*512 + dt*32);
    }
    // ---- MFMA phase: gh^T = W x h ----
    f32x4 acc0 = {0.f,0.f,0.f,0.f}, acc1 = {0.f,0.f,0.f,0.f};
    f32x4 acc2 = {0.f,0.f,0.f,0.f}, acc3 = {0.f,0.f,0.f,0.f};
    f32x4 acc4 = {bn[0][0], bn[0][1], bn[0][2], bn[0][3]};
    f32x4 acc5 = {bn[1][0], bn[1][1], bn[1][2], bn[1][3]};
    #pragma unroll
    for (int kc = 0; kc < 8; ++kc){
      f16x8 bf = *(const f16x8*)(h16b + ((fr*512 + kc*64 + lq*16) ^ ((fr&7)<<4)));
      acc0 = __builtin_amdgcn_mfma_f32_16x16x32_f16(wf[0][kc], bf, acc0,0,0,0);
      acc1 = __builtin_amdgcn_mfma_f32_16x16x32_f16(wf[1][kc], bf, acc1,0,0,0);
      acc2 = __builtin_amdgcn_mfma_f32_16x16x32_f16(wf[2][kc], bf, acc2,0,0,0);
      acc3 = __builtin_amdgcn_mfma_f32_16x16x32_f16(wf[3][kc], bf, acc3,0,0,0);
      acc4 = __builtin_amdgcn_mfma_f32_16x16x32_f16(wf[4][kc], bf, acc4,0,0,0);
      acc5 = __builtin_amdgcn_mfma_f32_16x16x32_f16(wf[5][kc], bf, acc5,0,0,0);
    }
    asm volatile("s_waitcnt lgkmcnt(0)" ::: "memory");
    __builtin_amdgcn_s_barrier();
    // ---- activation (in-register; lane owns graph gg, dims dbase+dt*16+v) ----
    #pragma unroll
    for (int dt = 0; dt < 2; ++dt){
      f32x4 gir = cvt4(gc[dt]);
      f32x4 giz = cvt4(gc[2+dt]);
      f32x4 gin = cvt4(gc[4+dt]);
      f32x4 ar = dt ? acc1 : acc0;
      f32x4 az = dt ? acc3 : acc2;
      f32x4 an = dt ? acc5 : acc4;
      float h_[4];
      #pragma unroll
      for (int v = 0; v < 4; ++v){
        float r  = sigf(gir[v] + ar[v]);
        float z  = sigf(giz[v] + az[v]);
        float nn = tanhff(gin[v] + r*an[v]);
        float h  = z*(ho[dt][v] - nn) + nn;
        ho[dt][v] = h; h_[v] = h;
      }
      *(uint2*)(h16b + ((fr*512 + w*64 + dt*32 + lq*8) ^ ((fr&7)<<4)))
          = pack4(h_[0], h_[1], h_[2], h_[3]);
      if (s == 254)
        *(float4*)(bwd1 + (size_t)gg*DIM + dbase + dt*16)
            = make_float4(h_[0], h_[1], h_[2], h_[3]);
      if (s == 255)
        *(float4*)(bwd0 + (size_t)gg*DIM + dbase + dt*16)
            = make_float4(h_[0], h_[1], h_[2], h_[3]);
    }
    #pragma unroll
    for (int i = 0; i < 6; ++i) gc[i] = gn[i];
    asm volatile("s_waitcnt lgkmcnt(0)" ::: "memory");
    __builtin_amdgcn_s_barrier();
  }
}

// ---------------- D2: forward GRU, only steps 0,1 needed ----------------
__global__ __launch_bounds__(768) void k_gru_fwd(
      const float* __restrict__ emds, const float* __restrict__ gbias,
      const float* __restrict__ h0,
      const float* __restrict__ wihf, const float* __restrict__ whhf,
      const float* __restrict__ bihf, const float* __restrict__ bhhf,
      float* __restrict__ fwd0, float* __restrict__ fwd1){
  int j = threadIdx.x;
  int b = blockIdx.x;
  __shared__ float xv[2][256];
  __shared__ float hcur[256];
  __shared__ float frz[512];
  __shared__ float fhn[256], fin[256];
  if (j < 256){
    float bi = gbias[j];
    xv[0][j] = fmaxf(emds[(size_t)b*NN*DIM + 0*DIM + j] + bi, 0.f);
    xv[1][j] = fmaxf(emds[(size_t)b*NN*DIM + 1*DIM + j] + bi, 0.f);
    hcur[j] = h0[b*DIM + j];
  }
  __syncthreads();
  for (int st = 0; st < 2; ++st){
    const float4* wi = (const float4*)(wihf + (size_t)j*DIM);
    const float4* wh = (const float4*)(whhf + (size_t)j*DIM);
    float gi_ = bihf[j], gh_ = bhhf[j];
    #pragma unroll 8
    for (int c = 0; c < 64; ++c){
      float4 a = wi[c];
      gi_ += a.x*xv[st][c*4] + a.y*xv[st][c*4+1] + a.z*xv[st][c*4+2] + a.w*xv[st][c*4+3];
      float4 h4 = wh[c];
      gh_ += h4.x*hcur[c*4] + h4.y*hcur[c*4+1] + h4.z*hcur[c*4+2] + h4.w*hcur[c*4+3];
    }
    if (j < 512) frz[j] = gi_ + gh_;
    else { fhn[j-512] = gh_; fin[j-512] = gi_; }
    __syncthreads();
    if (j < 256){
      float r = 1.f/(1.f + __expf(-frz[j]));
      float z = 1.f/(1.f + __expf(-frz[256+j]));
      float n = tanhf(fin[j] + r*fhn[j]);
      float hnew = (1.f - z)*n + z*hcur[j];
      hcur[j] = hnew;
      if (st == 0) fwd0[b*DIM + j] = hnew; else fwd1[b*DIM + j] = hnew;
    }
    __syncthreads();
  }
}

// ---------------- E: head ----------------
__global__ __launch_bounds__(256) void k_head(const float* __restrict__ fwd0,
     const float* __restrict__ fwd1, const float* __restrict__ bwd1,
     const float* __restrict__ bwd0, const float* __restrict__ means,
     const int* __restrict__ rel,
     const float* __restrict__ W3, const float* __restrict__ b3,
     const float* __restrict__ W1, const float* __restrict__ b1,
     const float* __restrict__ W2, const float* __restrict__ b2,
     float* __restrict__ out){
  int b = blockIdx.x, d = threadIdx.x;
  __shared__ float cat0[512], cat1[512], feat[256];
  cat0[d] = fwd0[b*DIM+d]; cat0[256+d] = bwd0[b*DIM+d];
  cat1[d] = fwd1[b*DIM+d]; cat1[256+d] = bwd1[b*DIM+d];
  __syncthreads();
  const float4* w3r = (const float4*)(W3 + (size_t)d*512);
  float hd = b3[d], td = b3[d];
  #pragma unroll 8
  for (int c = 0; c < 128; ++c){
    float4 w = w3r[c];
    hd += w.x*cat0[c*4] + w.y*cat0[c*4+1] + w.z*cat0[c*4+2] + w.w*cat0[c*4+3];
    td += w.x*cat1[c*4] + w.y*cat1[c*4+1] + w.z*cat1[c*4+2] + w.w*cat1[c*4+3];
  }
  int lab = rel[b];
  feat[d] = fmaxf(hd, 0.f) + means[(size_t)lab*DIM + d] - fmaxf(td, 0.f);
  __syncthreads();
  const float4* w1r = (const float4*)(W1 + (size_t)d*DIM);
  float s = b1[d];
  #pragma unroll 8
  for (int c = 0; c < 64; ++c){
    float4 w = w1r[c];
    s += w.x*feat[c*4] + w.y*feat[c*4+1] + w.z*feat[c*4+2] + w.w*feat[c*4+3];
  }
  float v = W2[d] * s;
  #pragma unroll
  for (int o = 32; o > 0; o >>= 1) v += __shfl_down(v, o, 64);
  __shared__ float red[4];
  if ((d & 63) == 0) red[d >> 6] = v;
  __syncthreads();
  if (d == 0) out[b] = red[0] + red[1] + red[2] + red[3] + b2[0];
}

extern "C" void kernel_launch(void* const* d_in, const int* in_sizes, int n_in,
                              void* d_out, int out_size, void* d_ws, size_t ws_size,
                              hipStream_t stream){
  const float* lg_feats = (const float*)d_in[0];
  const int*   lg_type  = (const int*)d_in[1];
  const float* emds     = (const float*)d_in[2];
  const int*   rel      = (const int*)d_in[3];
  const float* gbias    = (const float*)d_in[4];
  const float* wihf     = (const float*)d_in[5];
  const float* whhf     = (const float*)d_in[6];
  const float* bihf     = (const float*)d_in[7];
  const float* bhhf     = (const float*)d_in[8];
  const float* wihb     = (const float*)d_in[9];
  const float* whhb     = (const float*)d_in[10];
  const float* bihb     = (const float*)d_in[11];
  const float* bhhb     = (const float*)d_in[12];
  const float* W3 = (const float*)d_in[13];
  const float* b3 = (const float*)d_in[14];
  const float* W1 = (const float*)d_in[15];
  const float* b1 = (const float*)d_in[16];
  const float* W2 = (const float*)d_in[17];
  const float* b2 = (const float*)d_in[18];
  float* out = (float*)d_out;

  char* ws = (char*)d_ws;
  size_t off = 0;
  auto alloc = [&](size_t bytes){ size_t o = off; off += (bytes + 255) & ~(size_t)255; return o; };
  size_t o_needed = alloc(256*4);
  size_t o_cntp   = alloc((size_t)NSPLIT*NRELS*4);
  size_t o_means  = alloc((size_t)NRELS*DIM*4);
  size_t o_h0     = alloc((size_t)BG*DIM*4);
  size_t o_X16    = alloc((size_t)MM*DIM*2);
  size_t o_wih16  = alloc((size_t)G3*DIM*2);
  size_t o_f0     = alloc((size_t)BG*DIM*4);
  size_t o_f1     = alloc((size_t)BG*DIM*4);
  size_t o_b1v    = alloc((size_t)BG*DIM*4);
  size_t o_b0v    = alloc((size_t)BG*DIM*4);
  // big region: partial sums (31 MB) first, then reused as gi16 (50 MB)
  size_t o_big    = alloc((size_t)MM*G3*2 > (size_t)NSPLIT*NRELS*DIM*4 ?
                          (size_t)MM*G3*2 : (size_t)NSPLIT*NRELS*DIM*4);
  (void)ws_size; (void)in_sizes; (void)n_in; (void)out_size;

  int*       needed = (int*)(ws + o_needed);
  int*       cntp   = (int*)(ws + o_cntp);
  float*     means  = (float*)(ws + o_means);
  float*     h0     = (float*)(ws + o_h0);
  _Float16*  X16    = (_Float16*)(ws + o_X16);
  f16x8*     wih16  = (f16x8*)(ws + o_wih16);
  float*     f0     = (float*)(ws + o_f0);
  float*     f1     = (float*)(ws + o_f1);
  float*     b1v    = (float*)(ws + o_b1v);
  float*     b0v    = (float*)(ws + o_b0v);
  float*     part   = (float*)(ws + o_big);
  _Float16*  gi16   = (_Float16*)(ws + o_big);

  // segment means first (so gemm can reuse the big region afterwards)
  k_needed<<<1, 256, 0, stream>>>(rel, needed);
  k_segsum<<<NSPLIT*4, 256, 0, stream>>>(lg_feats, lg_type, needed, part, cntp);
  k_means <<<NRELS, 256, 0, stream>>>(part, cntp, means);
  k_prep  <<<BG, 256, 0, stream>>>(emds, gbias, X16, h0);
  k_wconv <<<(G3*32)/256, 256, 0, stream>>>(wihb, wih16);
  k_gemm_gi<<<(MM/64)*(G3/64), 256, 0, stream>>>(X16, (const _Float16*)wih16,
                                                 bihb, bhhb, gi16);
  k_gru_bwd<<<BG/GPB, 512, 0, stream>>>(whhb, gi16, h0, bhhb, b1v, b0v);
  k_gru_fwd<<<BG, 768, 0, stream>>>(emds, gbias, h0, wihf, whhf, bihf, bhhf, f0, f1);
  k_head  <<<BG, 256, 0, stream>>>(f0, f1, b1v, b0v, means, rel,
                                   W3, b3, W1, b1, W2, b2, out);
}

// Round 4
// 935.855 us; speedup vs baseline: 1.1874x; 1.1874x over previous
//
#include <hip/hip_runtime.h>
#include <hip/hip_bf16.h>

typedef _Float16 h2_t  __attribute__((ext_vector_type(2)));
typedef _Float16 f16x8 __attribute__((ext_vector_type(8)));
typedef float    f32x4 __attribute__((ext_vector_type(4)));

#define NLG    196608
#define DIM    256
#define NRELS  237
#define BG     128
#define NN     256
#define MM     (BG*NN)      // 32768
#define G3     768          // 3*DIM
#define NSPLIT 128
#define GPB    16           // graphs per gru block

// ---------------- A0: needed-relation flags ----------------
__global__ void k_needed(const int* __restrict__ rel, int* __restrict__ needed){
  int t = threadIdx.x;
  needed[t] = 0;
  __syncthreads();
  if (t < BG) atomicOr(&needed[rel[t]], 1);
}

// ---------------- A1: skip-filtered partial segment sums ----------------
__global__ __launch_bounds__(256) void k_segsum(const float* __restrict__ lgf,
    const int* __restrict__ lgt, const int* __restrict__ needed,
    float* __restrict__ part, int* __restrict__ cntp){
  int split = blockIdx.x >> 2, chunk = blockIdx.x & 3;
  int c0 = chunk * 64;
  __shared__ float acc[NRELS*64];
  __shared__ int   cacc[NRELS];
  __shared__ int   sneed[NRELS];
  int t = threadIdx.x, lane = t & 63, wv = t >> 6;
  for (int i = t; i < NRELS*64; i += 256) acc[i] = 0.f;
  for (int i = t; i < NRELS; i += 256){ cacc[i] = 0; sneed[i] = needed[i]; }
  __syncthreads();
  const int RPS = NLG / NSPLIT;
  int rbase = split * RPS;
  for (int it = 0; it < RPS/8; ++it){
    int r0 = rbase + it*8 + wv*2;
    int ty0 = lgt[r0], ty1 = lgt[r0+1];
    int nd0 = sneed[ty0], nd1 = sneed[ty1];
    float v0 = 0.f, v1 = 0.f;
    if (nd0) v0 = lgf[(size_t)r0*DIM + c0 + lane];
    if (nd1) v1 = lgf[(size_t)(r0+1)*DIM + c0 + lane];
    if (nd0){ atomicAdd(&acc[ty0*64 + lane], v0);
              if (chunk==0 && lane==0) atomicAdd(&cacc[ty0], 1); }
    if (nd1){ atomicAdd(&acc[ty1*64 + lane], v1);
              if (chunk==0 && lane==0) atomicAdd(&cacc[ty1], 1); }
  }
  __syncthreads();
  for (int i = t; i < NRELS*64; i += 256){
    int r = i >> 6, d = i & 63;
    part[((size_t)split*NRELS + r)*DIM + c0 + d] = acc[i];
  }
  if (chunk==0) for (int i = t; i < NRELS; i += 256) cntp[split*NRELS + i] = cacc[i];
}

// ---------------- A2: reduce partials -> means ----------------
__global__ __launch_bounds__(256) void k_means(const float* __restrict__ part,
      const int* __restrict__ cntp, float* __restrict__ means){
  int r = blockIdx.x, d = threadIdx.x;
  float s = 0.f;
  for (int sp = 0; sp < NSPLIT; ++sp) s += part[((size_t)sp*NRELS + r)*DIM + d];
  int c = 0;
  for (int sp = 0; sp < NSPLIT; ++sp) c += cntp[sp*NRELS + r];
  means[r*DIM + d] = (c > 0) ? (s / (float)c) : 0.f;
}

// ---------------- B0: X16 = f16(relu(emds+bias)), h0 = max_n(node) ----------------
__global__ __launch_bounds__(256) void k_prep(const float* __restrict__ emds,
     const float* __restrict__ gbias, _Float16* __restrict__ X16, float* __restrict__ h0){
  int b = blockIdx.x, d = threadIdx.x;
  float bi = gbias[d];
  float mx = -3.4e38f;
  const float* src = emds + (size_t)b*NN*DIM + d;
  _Float16* dst = X16 + (size_t)b*NN*DIM + d;
  #pragma unroll 4
  for (int n = 0; n < NN; ++n){
    float v = src[(size_t)n*DIM];
    mx = fmaxf(mx, v);
    dst[(size_t)n*DIM] = (_Float16)fmaxf(v + bi, 0.f);
  }
  h0[b*DIM + d] = mx;
}

// ---------------- B2: w_ih_b -> f16 row-major [768][256] ----------------
__global__ __launch_bounds__(256) void k_wconv(const float* __restrict__ wih,
      f16x8* __restrict__ wih16){
  int tid = blockIdx.x*256 + threadIdx.x;   // 0..24575
  int c = tid / G3, j = tid - c*G3;
  const float* s2 = wih + (size_t)j*DIM + c*8;
  f16x8 v;
  #pragma unroll
  for (int e = 0; e < 8; ++e) v[e] = (_Float16)s2[e];
  wih16[(size_t)j*32 + c] = v;
}

// ---------------- C: gi16[t][g][768] = f16(X @ w_ih_b^T + b_ih_b + bhh_fold) ----
__global__ __launch_bounds__(256) void k_gemm_gi(const _Float16* __restrict__ X16,
        const _Float16* __restrict__ wih16, const float* __restrict__ bih,
        const float* __restrict__ bhh, _Float16* __restrict__ gi16){
  __shared__ __align__(16) _Float16 Xs[64*136];
  __shared__ __align__(16) _Float16 Ws[64*136];
  int m0 = (blockIdx.x / 12) * 64;
  int n0 = (blockIdx.x % 12) * 64;
  int tix = threadIdx.x;
  int w = tix >> 6, l = tix & 63;
  int wm = (w & 1) * 32, wn = (w >> 1) * 32;
  int fr = l & 15, kg = l >> 4;
  f32x4 acc[2][2] = {};
  for (int kh = 0; kh < 2; ++kh){
    if (kh) __syncthreads();
    for (int rnd = 0; rnd < 4; ++rnd){
      int chunk = rnd*256 + tix;
      int r = chunk >> 4, cc = chunk & 15;
      *(f16x8*)&Xs[r*136 + cc*8] = *(const f16x8*)&X16[(size_t)(m0+r)*DIM + kh*128 + cc*8];
      *(f16x8*)&Ws[r*136 + cc*8] = *(const f16x8*)&wih16[(size_t)(n0+r)*DIM + kh*128 + cc*8];
    }
    __syncthreads();
    #pragma unroll
    for (int kk = 0; kk < 4; ++kk){
      int kcol = kk*32 + kg*8;
      f16x8 a0 = *(const f16x8*)&Xs[(wm + fr)*136 + kcol];
      f16x8 a1 = *(const f16x8*)&Xs[(wm + 16 + fr)*136 + kcol];
      f16x8 b0 = *(const f16x8*)&Ws[(wn + fr)*136 + kcol];
      f16x8 b1 = *(const f16x8*)&Ws[(wn + 16 + fr)*136 + kcol];
      acc[0][0] = __builtin_amdgcn_mfma_f32_16x16x32_f16(a0,b0,acc[0][0],0,0,0);
      acc[0][1] = __builtin_amdgcn_mfma_f32_16x16x32_f16(a0,b1,acc[0][1],0,0,0);
      acc[1][0] = __builtin_amdgcn_mfma_f32_16x16x32_f16(a1,b0,acc[1][0],0,0,0);
      acc[1][1] = __builtin_amdgcn_mfma_f32_16x16x32_f16(a1,b1,acc[1][1],0,0,0);
    }
  }
  // bias (b_ih + b_hh fold for r,z gates i.e. col<512)
  int col0 = n0 + wn + fr;
  float bv0 = bih[col0] + (col0 < 512 ? bhh[col0] : 0.f);
  float bv1 = bih[col0+16] + (col0+16 < 512 ? bhh[col0+16] : 0.f);
  __syncthreads();
  _Float16* stage = (_Float16*)Xs;     // 64 x 72 (pad) staging
  #pragma unroll
  for (int i = 0; i < 2; ++i)
  #pragma unroll
  for (int j = 0; j < 2; ++j){
    float bv = j ? bv1 : bv0;
    #pragma unroll
    for (int v = 0; v < 4; ++v){
      int srow = wm + i*16 + kg*4 + v;
      int scol = wn + j*16 + fr;
      stage[srow*72 + scol] = (_Float16)(acc[i][j][v] + bv);
    }
  }
  __syncthreads();
  {
    int r = tix >> 2, ch = tix & 3;
    int t0 = m0 & 255, gg = m0 >> 8;
    const f16x8* src = (const f16x8*)(stage + r*72 + ch*16);
    _Float16* dst = gi16 + (size_t)(t0 + r)*(BG*G3) + (size_t)gg*G3 + n0 + ch*16;
    *(f16x8*)(dst)   = src[0];
    *(f16x8*)(dst+8) = src[1];
  }
}

// ---- helpers for k_gru_bwd ----
__device__ __forceinline__ uint2 pack4(float a, float b, float c, float d){
  h2_t p0; p0[0] = (_Float16)a; p0[1] = (_Float16)b;
  h2_t p1; p1[0] = (_Float16)c; p1[1] = (_Float16)d;
  uint2 r; r.x = __builtin_bit_cast(unsigned int, p0);
  r.y = __builtin_bit_cast(unsigned int, p1);
  return r;
}
__device__ __forceinline__ f32x4 cvt4(uint2 u){
  h2_t a = __builtin_bit_cast(h2_t, u.x), b = __builtin_bit_cast(h2_t, u.y);
  f32x4 r; r[0]=(float)a[0]; r[1]=(float)a[1]; r[2]=(float)b[0]; r[3]=(float)b[1];
  return r;
}
__device__ __forceinline__ float sigf(float x){
  return __builtin_amdgcn_rcpf(1.f + __expf(-x));
}
__device__ __forceinline__ float tanhff(float x){
  float e = __expf(2.f*x);
  return 1.f - 2.f*__builtin_amdgcn_rcpf(e + 1.f);
}

// ---------------- D: backward GRU, MFMA ----------------
// 8 blocks x 512 threads (8 waves = 2/SIMD -> 256 VGPR cap). Block owns 16
// graphs (= MFMA N dim). Wave w owns dims w*32..w*32+31 for all 3 gates.
// r,z gate weights resident in VGPRs (128 regs); n-gate weights in LDS
// (128 KB, swizzled); h double-buffered in LDS -> ONE barrier per step.
__global__ __launch_bounds__(512) void k_gru_bwd(
    const float* __restrict__ whh, const _Float16* __restrict__ gi16,
    const float* __restrict__ h0, const float* __restrict__ bhh,
    float* __restrict__ bwd1, float* __restrict__ bwd0){
  __shared__ __align__(16) _Float16 wnl[256*256];      // n-gate W, f16, swizzled
  __shared__ __align__(16) _Float16 h16[2][GPB*256];   // h state, f16, dbuf
  char* wnb = (char*)wnl;
  const int tid = threadIdx.x;
  const int w = tid >> 6, l = tid & 63;
  const int lq = l >> 4, fr = l & 15;
  const int gg = blockIdx.x * GPB + fr;
  const int dbase = w*32 + lq*4;

  // ---- stage n-gate weights (whh rows 512..767) -> LDS f16, swizzled ----
  for (int it = 0; it < 16; ++it){
    int chunk = it*512 + tid;          // 8192 chunks of 8 elems
    int r = chunk >> 5, k8 = chunk & 31;
    const float* s = whh + (size_t)(512 + r)*256 + k8*8;
    float4 x = *(const float4*)s, y = *(const float4*)(s+4);
    f16x8 f;
    f[0]=(_Float16)x.x; f[1]=(_Float16)x.y; f[2]=(_Float16)x.z; f[3]=(_Float16)x.w;
    f[4]=(_Float16)y.x; f[5]=(_Float16)y.y; f[6]=(_Float16)y.z; f[7]=(_Float16)y.w;
    *(f16x8*)(wnb + ((r*512 + k8*16) ^ ((r&7)<<4))) = f;
  }
  // ---- r,z weight fragments in VGPRs: wf[gate*2+dt][kc] (128 regs) ----
  f16x8 wf[4][8];
  #pragma unroll
  for (int gate = 0; gate < 2; ++gate)
  #pragma unroll
  for (int dt = 0; dt < 2; ++dt){
    const float* wr = whh + (size_t)(gate*256 + w*32 + dt*16 + fr)*256 + lq*8;
    #pragma unroll
    for (int kc = 0; kc < 8; ++kc){
      float4 x = *(const float4*)(wr + kc*32);
      float4 y = *(const float4*)(wr + kc*32 + 4);
      f16x8 f;
      f[0]=(_Float16)x.x; f[1]=(_Float16)x.y; f[2]=(_Float16)x.z; f[3]=(_Float16)x.w;
      f[4]=(_Float16)y.x; f[5]=(_Float16)y.y; f[6]=(_Float16)y.z; f[7]=(_Float16)y.w;
      wf[gate*2+dt][kc] = f;
    }
  }
  // ---- h_old (f32 regs), h16[0] init, b_hh_n regs ----
  float ho[2][4];
  float bn[2][4];
  #pragma unroll
  for (int dt = 0; dt < 2; ++dt){
    float4 h4 = *(const float4*)(h0 + (size_t)gg*DIM + dbase + dt*16);
    ho[dt][0]=h4.x; ho[dt][1]=h4.y; ho[dt][2]=h4.z; ho[dt][3]=h4.w;
    *(uint2*)((char*)h16[0] + ((fr*512 + w*64 + dt*32 + lq*8) ^ ((fr&7)<<4)))
        = pack4(h4.x, h4.y, h4.z, h4.w);
    float4 b4 = *(const float4*)(bhh + 512 + dbase + dt*16);
    bn[dt][0]=b4.x; bn[dt][1]=b4.y; bn[dt][2]=b4.z; bn[dt][3]=b4.w;
  }
  // ---- gi prefetch (t = 255) ----
  const char* gp = (const char*)gi16 + ((size_t)255*BG*G3 + (size_t)gg*G3 + dbase)*2;
  uint2 gc[6], gn[6];
  #pragma unroll
  for (int gate = 0; gate < 3; ++gate)
  #pragma unroll
  for (int dt = 0; dt < 2; ++dt)
    gc[gate*2+dt] = *(const uint2*)(gp + gate*512 + dt*32);
  __syncthreads();

  int cur = 0;
  for (int s = 0; s < 256; ++s){
    // prefetch next timestep's gi (in flight across the whole step)
    if (s < 255){
      gp -= (size_t)BG*G3*2;
      #pragma unroll
      for (int gate = 0; gate < 3; ++gate)
      #pragma unroll
      for (int dt = 0; dt < 2; ++dt)
        gn[gate*2+dt] = *(const uint2*)(gp + gate*512 + dt*32);
    }
    // ---- MFMA phase: gh^T = W x h (read h16[cur]) ----
    char* hbR = (char*)h16[cur];
    f32x4 acc0 = {0.f,0.f,0.f,0.f}, acc1 = {0.f,0.f,0.f,0.f};
    f32x4 acc2 = {0.f,0.f,0.f,0.f}, acc3 = {0.f,0.f,0.f,0.f};
    f32x4 acc4 = {bn[0][0], bn[0][1], bn[0][2], bn[0][3]};
    f32x4 acc5 = {bn[1][0], bn[1][1], bn[1][2], bn[1][3]};
    #pragma unroll
    for (int kc = 0; kc < 8; ++kc){
      f16x8 bf  = *(const f16x8*)(hbR + ((fr*512 + kc*64 + lq*16) ^ ((fr&7)<<4)));
      f16x8 wn0 = *(const f16x8*)(wnb + (((w*32 + fr)*512 + kc*64 + lq*16) ^ ((fr&7)<<4)));
      f16x8 wn1 = *(const f16x8*)(wnb + (((w*32 + 16 + fr)*512 + kc*64 + lq*16) ^ ((fr&7)<<4)));
      acc0 = __builtin_amdgcn_mfma_f32_16x16x32_f16(wf[0][kc], bf, acc0,0,0,0);
      acc1 = __builtin_amdgcn_mfma_f32_16x16x32_f16(wf[1][kc], bf, acc1,0,0,0);
      acc2 = __builtin_amdgcn_mfma_f32_16x16x32_f16(wf[2][kc], bf, acc2,0,0,0);
      acc3 = __builtin_amdgcn_mfma_f32_16x16x32_f16(wf[3][kc], bf, acc3,0,0,0);
      acc4 = __builtin_amdgcn_mfma_f32_16x16x32_f16(wn0, bf, acc4,0,0,0);
      acc5 = __builtin_amdgcn_mfma_f32_16x16x32_f16(wn1, bf, acc5,0,0,0);
    }
    // ---- activation (in-register), write next h into h16[cur^1] ----
    char* hbW = (char*)h16[cur^1];
    #pragma unroll
    for (int dt = 0; dt < 2; ++dt){
      f32x4 gir = cvt4(gc[dt]);
      f32x4 giz = cvt4(gc[2+dt]);
      f32x4 gin = cvt4(gc[4+dt]);
      f32x4 ar = dt ? acc1 : acc0;
      f32x4 az = dt ? acc3 : acc2;
      f32x4 an = dt ? acc5 : acc4;
      float h_[4];
      #pragma unroll
      for (int v = 0; v < 4; ++v){
        float r  = sigf(gir[v] + ar[v]);
        float z  = sigf(giz[v] + az[v]);
        float nn = tanhff(gin[v] + r*an[v]);
        float h  = z*(ho[dt][v] - nn) + nn;
        ho[dt][v] = h; h_[v] = h;
      }
      *(uint2*)(hbW + ((fr*512 + w*64 + dt*32 + lq*8) ^ ((fr&7)<<4)))
          = pack4(h_[0], h_[1], h_[2], h_[3]);
      if (s == 254)
        *(float4*)(bwd1 + (size_t)gg*DIM + dbase + dt*16)
            = make_float4(h_[0], h_[1], h_[2], h_[3]);
      if (s == 255)
        *(float4*)(bwd0 + (size_t)gg*DIM + dbase + dt*16)
            = make_float4(h_[0], h_[1], h_[2], h_[3]);
    }
    #pragma unroll
    for (int i = 0; i < 6; ++i) gc[i] = gn[i];
    // one barrier per step; drain only LDS ops (global prefetch stays in flight)
    asm volatile("s_waitcnt lgkmcnt(0)" ::: "memory");
    __builtin_amdgcn_s_barrier();
    cur ^= 1;
  }
}

// ---------------- D2: forward GRU, only steps 0,1 needed ----------------
__global__ __launch_bounds__(768) void k_gru_fwd(
      const float* __restrict__ emds, const float* __restrict__ gbias,
      const float* __restrict__ h0,
      const float* __restrict__ wihf, const float* __restrict__ whhf,
      const float* __restrict__ bihf, const float* __restrict__ bhhf,
      float* __restrict__ fwd0, float* __restrict__ fwd1){
  int j = threadIdx.x;
  int b = blockIdx.x;
  __shared__ float xv[2][256];
  __shared__ float hcur[256];
  __shared__ float frz[512];
  __shared__ float fhn[256], fin[256];
  if (j < 256){
    float bi = gbias[j];
    xv[0][j] = fmaxf(emds[(size_t)b*NN*DIM + 0*DIM + j] + bi, 0.f);
    xv[1][j] = fmaxf(emds[(size_t)b*NN*DIM + 1*DIM + j] + bi, 0.f);
    hcur[j] = h0[b*DIM + j];
  }
  __syncthreads();
  for (int st = 0; st < 2; ++st){
    const float4* wi = (const float4*)(wihf + (size_t)j*DIM);
    const float4* wh = (const float4*)(whhf + (size_t)j*DIM);
    float gi_ = bihf[j], gh_ = bhhf[j];
    #pragma unroll 8
    for (int c = 0; c < 64; ++c){
      float4 a = wi[c];
      gi_ += a.x*xv[st][c*4] + a.y*xv[st][c*4+1] + a.z*xv[st][c*4+2] + a.w*xv[st][c*4+3];
      float4 h4 = wh[c];
      gh_ += h4.x*hcur[c*4] + h4.y*hcur[c*4+1] + h4.z*hcur[c*4+2] + h4.w*hcur[c*4+3];
    }
    if (j < 512) frz[j] = gi_ + gh_;
    else { fhn[j-512] = gh_; fin[j-512] = gi_; }
    __syncthreads();
    if (j < 256){
      float r = 1.f/(1.f + __expf(-frz[j]));
      float z = 1.f/(1.f + __expf(-frz[256+j]));
      float n = tanhf(fin[j] + r*fhn[j]);
      float hnew = (1.f - z)*n + z*hcur[j];
      hcur[j] = hnew;
      if (st == 0) fwd0[b*DIM + j] = hnew; else fwd1[b*DIM + j] = hnew;
    }
    __syncthreads();
  }
}

// ---------------- E: head ----------------
__global__ __launch_bounds__(256) void k_head(const float* __restrict__ fwd0,
     const float* __restrict__ fwd1, const float* __restrict__ bwd1,
     const float* __restrict__ bwd0, const float* __restrict__ means,
     const int* __restrict__ rel,
     const float* __restrict__ W3, const float* __restrict__ b3,
     const float* __restrict__ W1, const float* __restrict__ b1,
     const float* __restrict__ W2, const float* __restrict__ b2,
     float* __restrict__ out){
  int b = blockIdx.x, d = threadIdx.x;
  __shared__ float cat0[512], cat1[512], feat[256];
  cat0[d] = fwd0[b*DIM+d]; cat0[256+d] = bwd0[b*DIM+d];
  cat1[d] = fwd1[b*DIM+d]; cat1[256+d] = bwd1[b*DIM+d];
  __syncthreads();
  const float4* w3r = (const float4*)(W3 + (size_t)d*512);
  float hd = b3[d], td = b3[d];
  #pragma unroll 8
  for (int c = 0; c < 128; ++c){
    float4 w = w3r[c];
    hd += w.x*cat0[c*4] + w.y*cat0[c*4+1] + w.z*cat0[c*4+2] + w.w*cat0[c*4+3];
    td += w.x*cat1[c*4] + w.y*cat1[c*4+1] + w.z*cat1[c*4+2] + w.w*cat1[c*4+3];
  }
  int lab = rel[b];
  feat[d] = fmaxf(hd, 0.f) + means[(size_t)lab*DIM + d] - fmaxf(td, 0.f);
  __syncthreads();
  const float4* w1r = (const float4*)(W1 + (size_t)d*DIM);
  float s = b1[d];
  #pragma unroll 8
  for (int c = 0; c < 64; ++c){
    float4 w = w1r[c];
    s += w.x*feat[c*4] + w.y*feat[c*4+1] + w.z*feat[c*4+2] + w.w*feat[c*4+3];
  }
  float v = W2[d] * s;
  #pragma unroll
  for (int o = 32; o > 0; o >>= 1) v += __shfl_down(v, o, 64);
  __shared__ float red[4];
  if ((d & 63) == 0) red[d >> 6] = v;
  __syncthreads();
  if (d == 0) out[b] = red[0] + red[1] + red[2] + red[3] + b2[0];
}

extern "C" void kernel_launch(void* const* d_in, const int* in_sizes, int n_in,
                              void* d_out, int out_size, void* d_ws, size_t ws_size,
                              hipStream_t stream){
  const float* lg_feats = (const float*)d_in[0];
  const int*   lg_type  = (const int*)d_in[1];
  const float* emds     = (const float*)d_in[2];
  const int*   rel      = (const int*)d_in[3];
  const float* gbias    = (const float*)d_in[4];
  const float* wihf     = (const float*)d_in[5];
  const float* whhf     = (const float*)d_in[6];
  const float* bihf     = (const float*)d_in[7];
  const float* bhhf     = (const float*)d_in[8];
  const float* wihb     = (const float*)d_in[9];
  const float* whhb     = (const float*)d_in[10];
  const float* bihb     = (const float*)d_in[11];
  const float* bhhb     = (const float*)d_in[12];
  const float* W3 = (const float*)d_in[13];
  const float* b3 = (const float*)d_in[14];
  const float* W1 = (const float*)d_in[15];
  const float* b1 = (const float*)d_in[16];
  const float* W2 = (const float*)d_in[17];
  const float* b2 = (const float*)d_in[18];
  float* out = (float*)d_out;

  char* ws = (char*)d_ws;
  size_t off = 0;
  auto alloc = [&](size_t bytes){ size_t o = off; off += (bytes + 255) & ~(size_t)255; return o; };
  size_t o_needed = alloc(256*4);
  size_t o_cntp   = alloc((size_t)NSPLIT*NRELS*4);
  size_t o_means  = alloc((size_t)NRELS*DIM*4);
  size_t o_h0     = alloc((size_t)BG*DIM*4);
  size_t o_X16    = alloc((size_t)MM*DIM*2);
  size_t o_wih16  = alloc((size_t)G3*DIM*2);
  size_t o_f0     = alloc((size_t)BG*DIM*4);
  size_t o_f1     = alloc((size_t)BG*DIM*4);
  size_t o_b1v    = alloc((size_t)BG*DIM*4);
  size_t o_b0v    = alloc((size_t)BG*DIM*4);
  // big region: partial sums (31 MB) first, then reused as gi16 (50 MB)
  size_t o_big    = alloc((size_t)MM*G3*2 > (size_t)NSPLIT*NRELS*DIM*4 ?
                          (size_t)MM*G3*2 : (size_t)NSPLIT*NRELS*DIM*4);
  (void)ws_size; (void)in_sizes; (void)n_in; (void)out_size;

  int*       needed = (int*)(ws + o_needed);
  int*       cntp   = (int*)(ws + o_cntp);
  float*     means  = (float*)(ws + o_means);
  float*     h0     = (float*)(ws + o_h0);
  _Float16*  X16    = (_Float16*)(ws + o_X16);
  f16x8*     wih16  = (f16x8*)(ws + o_wih16);
  float*     f0     = (float*)(ws + o_f0);
  float*     f1     = (float*)(ws + o_f1);
  float*     b1v    = (float*)(ws + o_b1v);
  float*     b0v    = (float*)(ws + o_b0v);
  float*     part   = (float*)(ws + o_big);
  _Float16*  gi16   = (_Float16*)(ws + o_big);

  // segment means first (so gemm can reuse the big region afterwards)
  k_needed<<<1, 256, 0, stream>>>(rel, needed);
  k_segsum<<<NSPLIT*4, 256, 0, stream>>>(lg_feats, lg_type, needed, part, cntp);
  k_means <<<NRELS, 256, 0, stream>>>(part, cntp, means);
  k_prep  <<<BG, 256, 0, stream>>>(emds, gbias, X16, h0);
  k_wconv <<<(G3*32)/256, 256, 0, stream>>>(wihb, wih16);
  k_gemm_gi<<<(MM/64)*(G3/64), 256, 0, stream>>>(X16, (const _Float16*)wih16,
                                                 bihb, bhhb, gi16);
  k_gru_bwd<<<BG/GPB, 512, 0, stream>>>(whhb, gi16, h0, bhhb, b1v, b0v);
  k_gru_fwd<<<BG, 768, 0, stream>>>(emds, gbias, h0, wihf, whhf, bihf, bhhf, f0, f1);
  k_head  <<<BG, 256, 0, stream>>>(f0, f1, b1v, b0v, means, rel,
                                   W3, b3, W1, b1, W2, b2, out);
}

// Round 5
// 823.351 us; speedup vs baseline: 1.3497x; 1.1366x over previous
//
#include <hip/hip_runtime.h>
#include <hip/hip_bf16.h>

typedef _Float16 h2_t  __attribute__((ext_vector_type(2)));
typedef _Float16 f16x8 __attribute__((ext_vector_type(8)));
typedef float    f32x4 __attribute__((ext_vector_type(4)));

#define NLG    196608
#define DIM    256
#define NRELS  237
#define BG     128
#define NN     256
#define MM     (BG*NN)      // 32768
#define G3     768          // 3*DIM
#define NSPLIT 128
#define GPB    16           // graphs per gru block

// ---------------- A0: needed-relation flags ----------------
__global__ void k_needed(const int* __restrict__ rel, int* __restrict__ needed){
  int t = threadIdx.x;
  needed[t] = 0;
  __syncthreads();
  if (t < BG) atomicOr(&needed[rel[t]], 1);
}

// ---------------- A1: skip-filtered partial segment sums ----------------
__global__ __launch_bounds__(256) void k_segsum(const float* __restrict__ lgf,
    const int* __restrict__ lgt, const int* __restrict__ needed,
    float* __restrict__ part, int* __restrict__ cntp){
  int split = blockIdx.x >> 2, chunk = blockIdx.x & 3;
  int c0 = chunk * 64;
  __shared__ float acc[NRELS*64];
  __shared__ int   cacc[NRELS];
  __shared__ int   sneed[NRELS];
  int t = threadIdx.x, lane = t & 63, wv = t >> 6;
  for (int i = t; i < NRELS*64; i += 256) acc[i] = 0.f;
  for (int i = t; i < NRELS; i += 256){ cacc[i] = 0; sneed[i] = needed[i]; }
  __syncthreads();
  const int RPS = NLG / NSPLIT;
  int rbase = split * RPS;
  for (int it = 0; it < RPS/8; ++it){
    int r0 = rbase + it*8 + wv*2;
    int ty0 = lgt[r0], ty1 = lgt[r0+1];
    int nd0 = sneed[ty0], nd1 = sneed[ty1];
    float v0 = 0.f, v1 = 0.f;
    if (nd0) v0 = lgf[(size_t)r0*DIM + c0 + lane];
    if (nd1) v1 = lgf[(size_t)(r0+1)*DIM + c0 + lane];
    if (nd0){ atomicAdd(&acc[ty0*64 + lane], v0);
              if (chunk==0 && lane==0) atomicAdd(&cacc[ty0], 1); }
    if (nd1){ atomicAdd(&acc[ty1*64 + lane], v1);
              if (chunk==0 && lane==0) atomicAdd(&cacc[ty1], 1); }
  }
  __syncthreads();
  for (int i = t; i < NRELS*64; i += 256){
    int r = i >> 6, d = i & 63;
    part[((size_t)split*NRELS + r)*DIM + c0 + d] = acc[i];
  }
  if (chunk==0) for (int i = t; i < NRELS; i += 256) cntp[split*NRELS + i] = cacc[i];
}

// ---------------- A2: reduce partials -> means ----------------
__global__ __launch_bounds__(256) void k_means(const float* __restrict__ part,
      const int* __restrict__ cntp, float* __restrict__ means){
  int r = blockIdx.x, d = threadIdx.x;
  float s = 0.f;
  for (int sp = 0; sp < NSPLIT; ++sp) s += part[((size_t)sp*NRELS + r)*DIM + d];
  int c = 0;
  for (int sp = 0; sp < NSPLIT; ++sp) c += cntp[sp*NRELS + r];
  means[r*DIM + d] = (c > 0) ? (s / (float)c) : 0.f;
}

// ---------------- B0: X16 = f16(relu(emds+bias)), h0 = max_n(node) ----------------
__global__ __launch_bounds__(256) void k_prep(const float* __restrict__ emds,
     const float* __restrict__ gbias, _Float16* __restrict__ X16, float* __restrict__ h0){
  int b = blockIdx.x, d = threadIdx.x;
  float bi = gbias[d];
  float mx = -3.4e38f;
  const float* src = emds + (size_t)b*NN*DIM + d;
  _Float16* dst = X16 + (size_t)b*NN*DIM + d;
  #pragma unroll 4
  for (int n = 0; n < NN; ++n){
    float v = src[(size_t)n*DIM];
    mx = fmaxf(mx, v);
    dst[(size_t)n*DIM] = (_Float16)fmaxf(v + bi, 0.f);
  }
  h0[b*DIM + d] = mx;
}

// ---------------- B2: wih_b, whh_b -> f16 row-major [768][256] ----------------
__global__ __launch_bounds__(256) void k_wconv(const float* __restrict__ wih,
      const float* __restrict__ whh, _Float16* __restrict__ wih16,
      _Float16* __restrict__ whh16){
  int t = blockIdx.x*256 + threadIdx.x;      // 0..49151
  const float* src; _Float16* dst; int i;
  if (t < 24576){ src = wih; dst = wih16; i = t*8; }
  else          { src = whh; dst = whh16; i = (t-24576)*8; }
  float4 a = *(const float4*)(src + i);
  float4 b = *(const float4*)(src + i + 4);
  f16x8 v;
  v[0]=(_Float16)a.x; v[1]=(_Float16)a.y; v[2]=(_Float16)a.z; v[3]=(_Float16)a.w;
  v[4]=(_Float16)b.x; v[5]=(_Float16)b.y; v[6]=(_Float16)b.z; v[7]=(_Float16)b.w;
  *(f16x8*)(dst + i) = v;
}

// ---------------- C: gi16[t][g][768] = f16(X @ w_ih_b^T + b_ih_b + bhh_fold) ----
__global__ __launch_bounds__(256) void k_gemm_gi(const _Float16* __restrict__ X16,
        const _Float16* __restrict__ wih16, const float* __restrict__ bih,
        const float* __restrict__ bhh, _Float16* __restrict__ gi16){
  __shared__ __align__(16) _Float16 Xs[64*136];
  __shared__ __align__(16) _Float16 Ws[64*136];
  int m0 = (blockIdx.x / 12) * 64;
  int n0 = (blockIdx.x % 12) * 64;
  int tix = threadIdx.x;
  int w = tix >> 6, l = tix & 63;
  int wm = (w & 1) * 32, wn = (w >> 1) * 32;
  int fr = l & 15, kg = l >> 4;
  f32x4 acc[2][2] = {};
  for (int kh = 0; kh < 2; ++kh){
    if (kh) __syncthreads();
    for (int rnd = 0; rnd < 4; ++rnd){
      int chunk = rnd*256 + tix;
      int r = chunk >> 4, cc = chunk & 15;
      *(f16x8*)&Xs[r*136 + cc*8] = *(const f16x8*)&X16[(size_t)(m0+r)*DIM + kh*128 + cc*8];
      *(f16x8*)&Ws[r*136 + cc*8] = *(const f16x8*)&wih16[(size_t)(n0+r)*DIM + kh*128 + cc*8];
    }
    __syncthreads();
    #pragma unroll
    for (int kk = 0; kk < 4; ++kk){
      int kcol = kk*32 + kg*8;
      f16x8 a0 = *(const f16x8*)&Xs[(wm + fr)*136 + kcol];
      f16x8 a1 = *(const f16x8*)&Xs[(wm + 16 + fr)*136 + kcol];
      f16x8 b0 = *(const f16x8*)&Ws[(wn + fr)*136 + kcol];
      f16x8 b1 = *(const f16x8*)&Ws[(wn + 16 + fr)*136 + kcol];
      acc[0][0] = __builtin_amdgcn_mfma_f32_16x16x32_f16(a0,b0,acc[0][0],0,0,0);
      acc[0][1] = __builtin_amdgcn_mfma_f32_16x16x32_f16(a0,b1,acc[0][1],0,0,0);
      acc[1][0] = __builtin_amdgcn_mfma_f32_16x16x32_f16(a1,b0,acc[1][0],0,0,0);
      acc[1][1] = __builtin_amdgcn_mfma_f32_16x16x32_f16(a1,b1,acc[1][1],0,0,0);
    }
  }
  int col0 = n0 + wn + fr;
  float bv0 = bih[col0] + (col0 < 512 ? bhh[col0] : 0.f);
  float bv1 = bih[col0+16] + (col0+16 < 512 ? bhh[col0+16] : 0.f);
  __syncthreads();
  _Float16* stage = (_Float16*)Xs;
  #pragma unroll
  for (int i = 0; i < 2; ++i)
  #pragma unroll
  for (int j = 0; j < 2; ++j){
    float bv = j ? bv1 : bv0;
    #pragma unroll
    for (int v = 0; v < 4; ++v){
      int srow = wm + i*16 + kg*4 + v;
      int scol = wn + j*16 + fr;
      stage[srow*72 + scol] = (_Float16)(acc[i][j][v] + bv);
    }
  }
  __syncthreads();
  {
    int r = tix >> 2, ch = tix & 3;
    int t0 = m0 & 255, gg = m0 >> 8;
    const f16x8* src = (const f16x8*)(stage + r*72 + ch*16);
    _Float16* dst = gi16 + (size_t)(t0 + r)*(BG*G3) + (size_t)gg*G3 + n0 + ch*16;
    *(f16x8*)(dst)   = src[0];
    *(f16x8*)(dst+8) = src[1];
  }
}

// ---- helpers ----
__device__ __forceinline__ uint2 pack4(float a, float b, float c, float d){
  h2_t p0; p0[0] = (_Float16)a; p0[1] = (_Float16)b;
  h2_t p1; p1[0] = (_Float16)c; p1[1] = (_Float16)d;
  uint2 r; r.x = __builtin_bit_cast(unsigned int, p0);
  r.y = __builtin_bit_cast(unsigned int, p1);
  return r;
}
__device__ __forceinline__ f32x4 cvt4(uint2 u){
  h2_t a = __builtin_bit_cast(h2_t, u.x), b = __builtin_bit_cast(h2_t, u.y);
  f32x4 r; r[0]=(float)a[0]; r[1]=(float)a[1]; r[2]=(float)b[0]; r[3]=(float)b[1];
  return r;
}
__device__ __forceinline__ float sigf(float x){
  return __builtin_amdgcn_rcpf(1.f + __expf(-x));
}
__device__ __forceinline__ float tanhff(float x){
  float e = __expf(2.f*x);
  return 1.f - 2.f*__builtin_amdgcn_rcpf(e + 1.f);
}

// ---------------- D: fused GRU ----------------
// blocks 0..7: backward chains, 512 thr, MFMA. 5/6 weight tiles in VGPRs
// (160 regs), 1 tile (n-gate,dt1) in LDS; all LDS accesses lane-linear
// (conflict-free); h double-buffered; one lgkm-only barrier per step.
// blocks 8..135: forward GRU, 2 steps only, f32 VALU.
__global__ __launch_bounds__(512) void k_gru(
    const _Float16* __restrict__ whh16, const _Float16* __restrict__ gi16,
    const float* __restrict__ h0, const float* __restrict__ bhh,
    float* __restrict__ bwd1, float* __restrict__ bwd0,
    const float* __restrict__ emds, const float* __restrict__ gbias,
    const float* __restrict__ wihf, const float* __restrict__ whhf,
    const float* __restrict__ bihf, const float* __restrict__ bhhf,
    float* __restrict__ fwd0, float* __restrict__ fwd1){
  if (blockIdx.x < 8){
    __shared__ __align__(16) _Float16 wnl[8*4096];    // 64 KB, read-order linear
    __shared__ __align__(16) _Float16 hls[2][4096];   // 2 x 8 KB: [k/8][g][8]
    char* wnb = (char*)wnl;
    const int tid = threadIdx.x;
    const int w = tid >> 6, l = tid & 63;
    const int lq = l >> 4, fr = l & 15;
    const int gg = blockIdx.x * GPB + fr;
    const int dbase = w*32 + lq*4;

    // stage n-gate dt=1 tile (rows 512+w*32+16+fr) in exact read order
    for (int it = 0; it < 8; ++it){
      int c2 = it*512 + tid;
      int w_ = c2 >> 9, kc_ = (c2 >> 6) & 7, l_ = c2 & 63;
      int row = 512 + w_*32 + 16 + (l_ & 15);
      int kcol = kc_*32 + (l_ >> 4)*8;
      *(f16x8*)(wnb + (size_t)c2*16) = *(const f16x8*)(whh16 + (size_t)row*256 + kcol);
    }
    // tiles 0..4 in regs: t5 = gate*2+dt for (0,0),(0,1),(1,0),(1,1),(2,0)
    f16x8 wf[5][8];
    #pragma unroll
    for (int t5 = 0; t5 < 5; ++t5){
      const int gate = t5 >> 1, dt = t5 & 1;
      const _Float16* wr = whh16 + (size_t)(gate*256 + w*32 + dt*16 + fr)*256 + lq*8;
      #pragma unroll
      for (int kc = 0; kc < 8; ++kc)
        wf[t5][kc] = *(const f16x8*)(wr + kc*32);
    }
    // h_old f32 regs, h16[0] init, b_hh_n regs
    float ho[2][4], bn[2][4];
    {
      char* hb0 = (char*)hls[0];
      #pragma unroll
      for (int dt = 0; dt < 2; ++dt){
        float4 h4 = *(const float4*)(h0 + (size_t)gg*DIM + dbase + dt*16);
        ho[dt][0]=h4.x; ho[dt][1]=h4.y; ho[dt][2]=h4.z; ho[dt][3]=h4.w;
        *(uint2*)(hb0 + (w*4 + dt*2 + (lq>>1))*256 + fr*16 + (lq&1)*8)
            = pack4(h4.x,h4.y,h4.z,h4.w);
        float4 b4 = *(const float4*)(bhh + 512 + dbase + dt*16);
        bn[dt][0]=b4.x; bn[dt][1]=b4.y; bn[dt][2]=b4.z; bn[dt][3]=b4.w;
      }
    }
    // gi prefetch (t = 255)
    const char* gp = (const char*)gi16 + ((size_t)255*BG*G3 + (size_t)gg*G3 + dbase)*2;
    uint2 gc[6], gn[6];
    #pragma unroll
    for (int g2 = 0; g2 < 3; ++g2)
    #pragma unroll
    for (int dt = 0; dt < 2; ++dt)
      gc[g2*2+dt] = *(const uint2*)(gp + g2*512 + dt*32);
    __syncthreads();

    int cur = 0;
    for (int s = 0; s < 256; ++s){
      if (s < 255){
        gp -= (size_t)BG*G3*2;
        #pragma unroll
        for (int g2 = 0; g2 < 3; ++g2)
        #pragma unroll
        for (int dt = 0; dt < 2; ++dt)
          gn[g2*2+dt] = *(const uint2*)(gp + g2*512 + dt*32);
      }
      // MFMA phase: all ds_reads are base + kc*1024 + l*16 (lane-linear)
      const char* hb = (const char*)hls[cur];
      f32x4 acc0 = {}, acc1 = {}, acc2 = {}, acc3 = {}, acc4 = {}, acc5 = {};
      #pragma unroll
      for (int kc = 0; kc < 8; ++kc){
        f16x8 bf = *(const f16x8*)(hb + kc*1024 + l*16);
        f16x8 wn = *(const f16x8*)(wnb + w*8192 + kc*1024 + l*16);
        acc0 = __builtin_amdgcn_mfma_f32_16x16x32_f16(wf[0][kc], bf, acc0,0,0,0);
        acc1 = __builtin_amdgcn_mfma_f32_16x16x32_f16(wf[1][kc], bf, acc1,0,0,0);
        acc2 = __builtin_amdgcn_mfma_f32_16x16x32_f16(wf[2][kc], bf, acc2,0,0,0);
        acc3 = __builtin_amdgcn_mfma_f32_16x16x32_f16(wf[3][kc], bf, acc3,0,0,0);
        acc4 = __builtin_amdgcn_mfma_f32_16x16x32_f16(wf[4][kc], bf, acc4,0,0,0);
        acc5 = __builtin_amdgcn_mfma_f32_16x16x32_f16(wn,        bf, acc5,0,0,0);
      }
      // activation: lane owns graph fr (col), dims w*32+dt*16+lq*4+v (C row)
      char* hw = (char*)hls[cur^1];
      #pragma unroll
      for (int dt = 0; dt < 2; ++dt){
        f32x4 gir = cvt4(gc[dt]);
        f32x4 giz = cvt4(gc[2+dt]);
        f32x4 gin = cvt4(gc[4+dt]);
        f32x4 ar = dt ? acc1 : acc0;
        f32x4 az = dt ? acc3 : acc2;
        f32x4 an = dt ? acc5 : acc4;
        float h_[4];
        #pragma unroll
        for (int v = 0; v < 4; ++v){
          float r  = sigf(gir[v] + ar[v]);
          float z  = sigf(giz[v] + az[v]);
          float nn = tanhff(gin[v] + r*(an[v] + bn[dt][v]));
          float h  = z*(ho[dt][v] - nn) + nn;
          ho[dt][v] = h; h_[v] = h;
        }
        *(uint2*)(hw + (w*4 + dt*2 + (lq>>1))*256 + fr*16 + (lq&1)*8)
            = pack4(h_[0],h_[1],h_[2],h_[3]);
        if (s == 254)
          *(float4*)(bwd1 + (size_t)gg*DIM + dbase + dt*16)
              = make_float4(h_[0],h_[1],h_[2],h_[3]);
        if (s == 255)
          *(float4*)(bwd0 + (size_t)gg*DIM + dbase + dt*16)
              = make_float4(h_[0],h_[1],h_[2],h_[3]);
      }
      #pragma unroll
      for (int i = 0; i < 6; ++i) gc[i] = gn[i];
      asm volatile("s_waitcnt lgkmcnt(0)" ::: "memory");
      __builtin_amdgcn_s_barrier();
      cur ^= 1;
    }
  } else {
    // ---- forward: fwd[0], fwd[1] only; 512 threads: rows j (r,z) + 256+j (n) ----
    const int b = blockIdx.x - 8;
    __shared__ __align__(16) float xv2[2][256];
    __shared__ __align__(16) float hc[256];
    __shared__ float frz2[512], fhn2[256], fin2[256];
    const int j = threadIdx.x;
    if (j < 256){
      float bi = gbias[j];
      xv2[0][j] = fmaxf(emds[(size_t)b*NN*DIM + j] + bi, 0.f);
      xv2[1][j] = fmaxf(emds[(size_t)b*NN*DIM + DIM + j] + bi, 0.f);
      hc[j] = h0[(size_t)b*DIM + j];
    }
    __syncthreads();
    for (int st = 0; st < 2; ++st){
      const float4* wi = (const float4*)(wihf + (size_t)j*DIM);
      const float4* wh = (const float4*)(whhf + (size_t)j*DIM);
      const int row2 = 256 + j;   // 512..767 for j>=256
      const float4* wi2 = (const float4*)(wihf + (size_t)row2*DIM);
      const float4* wh2 = (const float4*)(whhf + (size_t)row2*DIM);
      float g1 = bihf[j] + bhhf[j];
      float gi2 = 0.f, gh2 = 0.f;
      if (j >= 256){ gi2 = bihf[row2]; gh2 = bhhf[row2]; }
      #pragma unroll 4
      for (int c = 0; c < 64; ++c){
        float4 x4 = *(const float4*)&xv2[st][c*4];
        float4 h4 = *(const float4*)&hc[c*4];
        float4 a = wi[c], hh = wh[c];
        g1 += a.x*x4.x + a.y*x4.y + a.z*x4.z + a.w*x4.w;
        g1 += hh.x*h4.x + hh.y*h4.y + hh.z*h4.z + hh.w*h4.w;
        if (j >= 256){
          float4 a2 = wi2[c], hh2 = wh2[c];
          gi2 += a2.x*x4.x + a2.y*x4.y + a2.z*x4.z + a2.w*x4.w;
          gh2 += hh2.x*h4.x + hh2.y*h4.y + hh2.z*h4.z + hh2.w*h4.w;
        }
      }
      frz2[j] = g1;
      if (j >= 256){ fin2[j-256] = gi2; fhn2[j-256] = gh2; }
      __syncthreads();
      if (j < 256){
        float r = sigf(frz2[j]);
        float z = sigf(frz2[256+j]);
        float n = tanhff(fin2[j] + r*fhn2[j]);
        float hnew = z*(hc[j] - n) + n;
        hc[j] = hnew;
        if (st == 0) fwd0[(size_t)b*DIM + j] = hnew;
        else         fwd1[(size_t)b*DIM + j] = hnew;
      }
      __syncthreads();
    }
  }
}

// ---------------- E: head ----------------
__global__ __launch_bounds__(256) void k_head(const float* __restrict__ fwd0,
     const float* __restrict__ fwd1, const float* __restrict__ bwd1,
     const float* __restrict__ bwd0, const float* __restrict__ means,
     const int* __restrict__ rel,
     const float* __restrict__ W3, const float* __restrict__ b3,
     const float* __restrict__ W1, const float* __restrict__ b1,
     const float* __restrict__ W2, const float* __restrict__ b2,
     float* __restrict__ out){
  int b = blockIdx.x, d = threadIdx.x;
  __shared__ float cat0[512], cat1[512], feat[256];
  cat0[d] = fwd0[b*DIM+d]; cat0[256+d] = bwd0[b*DIM+d];
  cat1[d] = fwd1[b*DIM+d]; cat1[256+d] = bwd1[b*DIM+d];
  __syncthreads();
  const float4* w3r = (const float4*)(W3 + (size_t)d*512);
  float hd = b3[d], td = b3[d];
  #pragma unroll 8
  for (int c = 0; c < 128; ++c){
    float4 w = w3r[c];
    hd += w.x*cat0[c*4] + w.y*cat0[c*4+1] + w.z*cat0[c*4+2] + w.w*cat0[c*4+3];
    td += w.x*cat1[c*4] + w.y*cat1[c*4+1] + w.z*cat1[c*4+2] + w.w*cat1[c*4+3];
  }
  int lab = rel[b];
  feat[d] = fmaxf(hd, 0.f) + means[(size_t)lab*DIM + d] - fmaxf(td, 0.f);
  __syncthreads();
  const float4* w1r = (const float4*)(W1 + (size_t)d*DIM);
  float s = b1[d];
  #pragma unroll 8
  for (int c = 0; c < 64; ++c){
    float4 w = w1r[c];
    s += w.x*feat[c*4] + w.y*feat[c*4+1] + w.z*feat[c*4+2] + w.w*feat[c*4+3];
  }
  float v = W2[d] * s;
  #pragma unroll
  for (int o = 32; o > 0; o >>= 1) v += __shfl_down(v, o, 64);
  __shared__ float red[4];
  if ((d & 63) == 0) red[d >> 6] = v;
  __syncthreads();
  if (d == 0) out[b] = red[0] + red[1] + red[2] + red[3] + b2[0];
}

extern "C" void kernel_launch(void* const* d_in, const int* in_sizes, int n_in,
                              void* d_out, int out_size, void* d_ws, size_t ws_size,
                              hipStream_t stream){
  const float* lg_feats = (const float*)d_in[0];
  const int*   lg_type  = (const int*)d_in[1];
  const float* emds     = (const float*)d_in[2];
  const int*   rel      = (const int*)d_in[3];
  const float* gbias    = (const float*)d_in[4];
  const float* wihf     = (const float*)d_in[5];
  const float* whhf     = (const float*)d_in[6];
  const float* bihf     = (const float*)d_in[7];
  const float* bhhf     = (const float*)d_in[8];
  const float* wihb     = (const float*)d_in[9];
  const float* whhb     = (const float*)d_in[10];
  const float* bihb     = (const float*)d_in[11];
  const float* bhhb     = (const float*)d_in[12];
  const float* W3 = (const float*)d_in[13];
  const float* b3 = (const float*)d_in[14];
  const float* W1 = (const float*)d_in[15];
  const float* b1 = (const float*)d_in[16];
  const float* W2 = (const float*)d_in[17];
  const float* b2 = (const float*)d_in[18];
  float* out = (float*)d_out;

  char* ws = (char*)d_ws;
  size_t off = 0;
  auto alloc = [&](size_t bytes){ size_t o = off; off += (bytes + 255) & ~(size_t)255; return o; };
  size_t o_needed = alloc(256*4);
  size_t o_cntp   = alloc((size_t)NSPLIT*NRELS*4);
  size_t o_means  = alloc((size_t)NRELS*DIM*4);
  size_t o_h0     = alloc((size_t)BG*DIM*4);
  size_t o_X16    = alloc((size_t)MM*DIM*2);
  size_t o_wih16  = alloc((size_t)G3*DIM*2);
  size_t o_whh16  = alloc((size_t)G3*DIM*2);
  size_t o_f0     = alloc((size_t)BG*DIM*4);
  size_t o_f1     = alloc((size_t)BG*DIM*4);
  size_t o_b1v    = alloc((size_t)BG*DIM*4);
  size_t o_b0v    = alloc((size_t)BG*DIM*4);
  size_t o_big    = alloc((size_t)MM*G3*2 > (size_t)NSPLIT*NRELS*DIM*4 ?
                          (size_t)MM*G3*2 : (size_t)NSPLIT*NRELS*DIM*4);
  (void)ws_size; (void)in_sizes; (void)n_in; (void)out_size;

  int*       needed = (int*)(ws + o_needed);
  int*       cntp   = (int*)(ws + o_cntp);
  float*     means  = (float*)(ws + o_means);
  float*     h0     = (float*)(ws + o_h0);
  _Float16*  X16    = (_Float16*)(ws + o_X16);
  _Float16*  wih16  = (_Float16*)(ws + o_wih16);
  _Float16*  whh16  = (_Float16*)(ws + o_whh16);
  float*     f0     = (float*)(ws + o_f0);
  float*     f1     = (float*)(ws + o_f1);
  float*     b1v    = (float*)(ws + o_b1v);
  float*     b0v    = (float*)(ws + o_b0v);
  float*     part   = (float*)(ws + o_big);
  _Float16*  gi16   = (_Float16*)(ws + o_big);

  k_needed<<<1, 256, 0, stream>>>(rel, needed);
  k_segsum<<<NSPLIT*4, 256, 0, stream>>>(lg_feats, lg_type, needed, part, cntp);
  k_means <<<NRELS, 256, 0, stream>>>(part, cntp, means);
  k_prep  <<<BG, 256, 0, stream>>>(emds, gbias, X16, h0);
  k_wconv <<<192, 256, 0, stream>>>(wihb, whhb, wih16, whh16);
  k_gemm_gi<<<(MM/64)*(G3/64), 256, 0, stream>>>(X16, wih16, bihb, bhhb, gi16);
  k_gru   <<<8 + BG, 512, 0, stream>>>(whh16, gi16, h0, bhhb, b1v, b0v,
                                       emds, gbias, wihf, whhf, bihf, bhhf, f0, f1);
  k_head  <<<BG, 256, 0, stream>>>(f0, f1, b1v, b0v, means, rel,
                                   W3, b3, W1, b1, W2, b2, out);
}